// Round 5
// baseline (286.606 us; speedup 1.0000x reference)
//
#include <hip/hip_runtime.h>
#include <stdint.h>

// Problem constants: B=8, N=1024, IN_F=1024, E=256, H=4, A=64
typedef __attribute__((ext_vector_type(8))) short short8;
typedef __attribute__((ext_vector_type(4))) float f32x4;
typedef __attribute__((ext_vector_type(16))) float f32x16;

__device__ __forceinline__ float b2f(unsigned short u) {
    union { unsigned int i; float f; } v; v.i = ((unsigned int)u) << 16; return v.f;
}
__device__ __forceinline__ unsigned short f2b(float f) {
    union { float f; unsigned int i; } v; v.f = f;
    unsigned int u = v.i;
    u = (u + 0x7FFFu + ((u >> 16) & 1u)) >> 16;
    return (unsigned short)u;
}
__device__ __forceinline__ void glds16(const void* g, const void* l) {
    __builtin_amdgcn_global_load_lds(
        (const __attribute__((address_space(1))) unsigned int*)g,
        (__attribute__((address_space(3))) unsigned int*)l, 16, 0, 0);
}

// Detect input dtype: bf16-packed (flag=1) vs float32 (flag=0).
__global__ void detect_kern(const unsigned int* __restrict__ x, int* __restrict__ flag) {
    int tid = threadIdx.x;            // one wave (64 threads)
    unsigned int w = x[tid];
    unsigned int e = (w >> 7) & 0xFF;
    int isbf = (e >= 100 && e <= 140) ? 1 : 0;
    unsigned long long m = __ballot(isbf);
    if (tid == 0) flag[0] = (__popcll(m) >= 48) ? 1 : 0;
}

// Convert 8 elements/thread from (fp32 | bf16) to bf16.
__global__ void conv8(const void* __restrict__ in, unsigned short* __restrict__ out,
                      const int* __restrict__ flag, int total8) {
    int i = blockIdx.x * 256 + threadIdx.x;
    if (i >= total8) return;
    ushort4 o0, o1;
    if (*flag) {
        const ushort4* p = (const ushort4*)in + (size_t)i * 2;
        o0 = p[0]; o1 = p[1];
    } else {
        const float4* p = (const float4*)in + (size_t)i * 2;
        float4 a = p[0], b = p[1];
        o0.x = f2b(a.x); o0.y = f2b(a.y); o0.z = f2b(a.z); o0.w = f2b(a.w);
        o1.x = f2b(b.x); o1.y = f2b(b.y); o1.z = f2b(b.z); o1.w = f2b(b.w);
    }
    ((ushort4*)out)[(size_t)i * 2]     = o0;
    ((ushort4*)out)[(size_t)i * 2 + 1] = o1;
}

// LDS-tiled transpose + convert: in[bt][1024][C] -> out[bt][C][1024] (bf16).
__global__ __launch_bounds__(256) void t2_kern(
        const void* __restrict__ in, unsigned short* __restrict__ out,
        const int* __restrict__ flag, int C) {
    __shared__ unsigned int tile[64 * 65];
    int t = threadIdx.x;
    int c0 = blockIdx.x * 64;
    int r0 = blockIdx.y * 64;
    int bt = blockIdx.z;
    int rl = t >> 2;
    int cc = (t & 3) * 16;
    size_t ibase = ((size_t)bt * 1024 + (r0 + rl)) * C + c0 + cc;
    unsigned short v[16];
    if (*flag) {
        const unsigned short* p = (const unsigned short*)in + ibase;
        short8 a = *(const short8*)p;
        short8 b = *(const short8*)(p + 8);
#pragma unroll
        for (int j = 0; j < 8; j++) { v[j] = (unsigned short)a[j]; v[8 + j] = (unsigned short)b[j]; }
    } else {
        const float* p = (const float*)in + ibase;
#pragma unroll
        for (int j = 0; j < 16; j++) v[j] = f2b(p[j]);
    }
#pragma unroll
    for (int j = 0; j < 16; j++)
        tile[(cc + j) * 65 + rl] = v[j];
    __syncthreads();
    int cl = t >> 2;
    int rch = (t & 3) * 16;
    unsigned short o[16];
#pragma unroll
    for (int j = 0; j < 16; j++)
        o[j] = (unsigned short)tile[cl * 65 + rch + j];
    unsigned short* op = out + ((size_t)bt * C + (c0 + cl)) * 1024 + r0 + rch;
#pragma unroll
    for (int q = 0; q < 4; q++) {
        ushort4 s; s.x = o[q*4]; s.y = o[q*4+1]; s.z = o[q*4+2]; s.w = o[q*4+3];
        ((ushort4*)op)[q] = s;
    }
}

// Pack adj (8M int32 0/1) into a bitmask, 1 bit per element, via ballot.
__global__ void pack_adj(const int* __restrict__ adj,
                         unsigned long long* __restrict__ mask) {
    int gid = blockIdx.x * 256 + threadIdx.x;
    int lane = threadIdx.x & 63;
    unsigned long long m = __ballot(adj[gid] > 0);
    if (lane == 0) mask[gid >> 6] = m;
}

// K1: Wh = x @ W[h]  (M=8192, N=1024=H*E, K=1024), writes WhT[hb][e][m] bf16.
__global__ __launch_bounds__(256) void k1_gemm(
        const unsigned short* __restrict__ x,
        const unsigned short* __restrict__ WT,      // [H][E=256][K=1024]
        unsigned short* __restrict__ WhT) {         // [H*8+b][256][1024]
    __shared__ unsigned short smA[8 * 512];
    __shared__ unsigned short smB[8 * 512];
    int tid = threadIdx.x;
    int w = tid >> 6, lane = tid & 63;
    int lr = lane & 15, lq = lane >> 4;
    int col0 = blockIdx.x * 128;
    int row0 = blockIdx.y * 128;
    int h = col0 >> 8;
    int e_base = col0 & 255;
    int b = row0 >> 10;
    int m_base = row0 & 1023;
    int wr = w >> 1, wc = w & 1;

    f32x4 acc[4][4] = {};

    for (int k0 = 0; k0 < 1024; k0 += 32) {
        __syncthreads();
#pragma unroll
        for (int s = 0; s < 2; s++) {
            int g = 2 * w + s;
            const unsigned short* srcA =
                x + (size_t)(row0 + g * 16 + lr) * 1024 + k0 + lq * 8;
            glds16(srcA, &smA[g * 512]);
            const unsigned short* srcB =
                WT + (size_t)(h * 256 + e_base + g * 16 + lr) * 1024 + k0 + lq * 8;
            glds16(srcB, &smB[g * 512]);
        }
        __syncthreads();
        short8 af[4], bf[4];
#pragma unroll
        for (int i = 0; i < 4; i++)
            af[i] = *(const short8*)&smA[(wr * 4 + i) * 512 + lane * 8];
#pragma unroll
        for (int j = 0; j < 4; j++)
            bf[j] = *(const short8*)&smB[(wc * 4 + j) * 512 + lane * 8];
#pragma unroll
        for (int i = 0; i < 4; i++)
#pragma unroll
            for (int j = 0; j < 4; j++)
                acc[i][j] = __builtin_amdgcn_mfma_f32_16x16x32_bf16(
                    af[i], bf[j], acc[i][j], 0, 0, 0);
    }

    int hb = h * 8 + b;
#pragma unroll
    for (int i = 0; i < 4; i++) {
#pragma unroll
        for (int j = 0; j < 4; j++) {
            int e = e_base + (wc * 4 + j) * 16 + lr;
            int m = m_base + (wr * 4 + i) * 16 + lq * 4;
            ushort4 vs;
            vs.x = f2b(acc[i][j][0]);
            vs.y = f2b(acc[i][j][1]);
            vs.z = f2b(acc[i][j][2]);
            vs.w = f2b(acc[i][j][3]);
            *(ushort4*)&WhT[(size_t)(hb * 256 + e) * 1024 + m] = vs;
        }
    }
}

// K1b: f1[hb][n] = sum_e WhT[hb][e][n]*a1[h][e]; f2 likewise.
__global__ void k1b_f12(const unsigned short* __restrict__ WhT,
                        const unsigned short* __restrict__ a1,
                        const unsigned short* __restrict__ a2,
                        float* __restrict__ f1, float* __restrict__ f2) {
    int hb = blockIdx.y;
    int n = blockIdx.x * 256 + threadIdx.x;
    int h = hb >> 3;
    float s1 = 0.f, s2 = 0.f;
    for (int e = 0; e < 256; e++) {
        float wv = b2f(WhT[(size_t)(hb * 256 + e) * 1024 + n]);
        s1 += wv * b2f(a1[h * 256 + e]);
        s2 += wv * b2f(a2[h * 256 + e]);
    }
    f1[hb * 1024 + n] = s1;
    f2[hb * 1024 + n] = s2;
}

// K2: masked-softmax attention + P@Wh + ELU -> feat[bn][h*256+e] bf16.
// Barrier-free: no LDS. Each wave = 32 rows x 128 e (e-half), 32x32x16 MFMA,
// B-frags loaded DIRECTLY global->VGPR (L2-hits via XCD swizzle; per-XCD
// working set 4 hb x 512 KB = 2 MB < 4 MB L2). The p/exp VALU block sits
// between load issue and MFMA use, hiding ~200cyc L2 latency without barriers.
// 2048 waves = 8/CU = 2/SIMD (acc 64 AGPR + ~120 VGPR).
__global__ __launch_bounds__(256, 2) void k2_attn(
        const unsigned short* __restrict__ WhT,
        const unsigned int* __restrict__ amask,     // [8][1024][32] u32 bit rows
        const float* __restrict__ f1, const float* __restrict__ f2,
        unsigned short* __restrict__ feat) {
    int tid = threadIdx.x;
    int w = tid >> 6, lane = tid & 63;
    int l5 = lane >> 5, l31 = lane & 31;
    int bid = blockIdx.x;
    int xcd = bid & 7, idx = bid >> 3;          // idx 0..63
    int hb = xcd + 8 * (idx >> 4);
    int sub = idx & 15;
    int wid = sub * 4 + w;                      // 0..63 within hb
    int rg = wid >> 1;                          // row-group 0..31
    int ehalf = wid & 1;
    int n0 = rg * 32;
    int h = hb >> 3, b = hb & 7;
    int row = n0 + l31;                         // this lane's attention row
    float f1n = f1[hb * 1024 + row];
    const unsigned short* whb = WhT + ((size_t)hb * 256 + ehalf * 128) * 1024;
    const unsigned int* amrow = amask + (size_t)(b * 1024 + row) * 32;
    const float* f2row = f2 + hb * 1024;

    f32x16 acc[4] = {};                         // e = ehalf*128 + et*32 + l31
    float den = 0.f;

    for (int m0 = 0; m0 < 1024; m0 += 32) {
        // B-frag direct loads: issue first (latency covered by p-compute below)
        short8 bfrag[4][2];
#pragma unroll
        for (int et = 0; et < 4; et++)
#pragma unroll
            for (int ks = 0; ks < 2; ks++)
                bfrag[et][ks] = *(const short8*)(whb
                    + (size_t)(et * 32 + l31) * 1024 + m0 + ks * 16 + l5 * 8);

        unsigned int mw = amrow[m0 >> 5];
        float4 fA0 = *(const float4*)(f2row + m0 + l5 * 8);
        float4 fA1 = *(const float4*)(f2row + m0 + l5 * 8 + 4);
        float4 fB0 = *(const float4*)(f2row + m0 + 16 + l5 * 8);
        float4 fB1 = *(const float4*)(f2row + m0 + 16 + l5 * 8 + 4);
        float fm[16] = {fA0.x,fA0.y,fA0.z,fA0.w, fA1.x,fA1.y,fA1.z,fA1.w,
                        fB0.x,fB0.y,fB0.z,fB0.w, fB1.x,fB1.y,fB1.z,fB1.w};
        short8 af[2];
#pragma unroll
        for (int ks = 0; ks < 2; ks++) {
#pragma unroll
            for (int j = 0; j < 8; j++) {
                float t_ = f1n + fm[ks * 8 + j];
                float e_ = fmaxf(t_, 0.2f * t_);                   // leaky relu
                float p  = ((mw >> (ks * 16 + l5 * 8 + j)) & 1u) ? __expf(e_) : 0.f;
                unsigned short pb = f2b(p);
                af[ks][j] = (short)pb;
                den += b2f(pb);      // bf16-rounded p: consistent num/denom
            }
        }
#pragma unroll
        for (int et = 0; et < 4; et++)
#pragma unroll
            for (int ks = 0; ks < 2; ks++)
                acc[et] = __builtin_amdgcn_mfma_f32_32x32x16_bf16(
                    af[ks], bfrag[et][ks], acc[et], 0, 0, 0);
    }

    // den: lane holds partial for row l31 over its k-half; combine halves
    den += __shfl_xor(den, 32, 64);

#pragma unroll
    for (int reg = 0; reg < 16; reg++) {
        int r = (reg & 3) + 8 * (reg >> 2) + 4 * l5;   // C-layout row (0..31)
        float dr = __shfl(den, r, 64);
        float rdr = 1.0f / dr;
        int nn = n0 + r;
#pragma unroll
        for (int et = 0; et < 4; et++) {
            int e = ehalf * 128 + et * 32 + l31;
            float v = acc[et][reg] * rdr;
            float o = v > 0.f ? v : __expf(v) - 1.f;   // elu
            feat[(size_t)(b * 1024 + nn) * 1024 + h * 256 + e] = f2b(o);
        }
    }
}

// K3: out = feat @ W_act + b_act  (M=8192, K=1024, N=64), out dtype per flag.
__global__ __launch_bounds__(256) void k3_out(
        const unsigned short* __restrict__ feat,
        const unsigned short* __restrict__ WactT,   // [64][1024]
        const unsigned short* __restrict__ bact,
        void* __restrict__ out, const int* __restrict__ flag) {
    __shared__ unsigned short smA[2 * 512];
    __shared__ unsigned short smB[4 * 512];
    int tid = threadIdx.x;
    int w = tid >> 6, lane = tid & 63;
    int lr = lane & 15, lq = lane >> 4;
    int row0 = blockIdx.x * 32;
    int g = w & 1, ch = w >> 1;
    int bf16out = *flag;
    f32x4 acc[2] = {};

    for (int k0 = 0; k0 < 1024; k0 += 32) {
        __syncthreads();
        if (w < 2) {
            const unsigned short* src =
                feat + (size_t)(row0 + w * 16 + lr) * 1024 + k0 + lq * 8;
            glds16(src, &smA[w * 512]);
        } else {
#pragma unroll
            for (int s = 0; s < 2; s++) {
                int t = (w - 2) * 2 + s;
                const unsigned short* src =
                    WactT + (size_t)(t * 16 + lr) * 1024 + k0 + lq * 8;
                glds16(src, &smB[t * 512]);
            }
        }
        __syncthreads();
        short8 af = *(const short8*)&smA[g * 512 + lane * 8];
#pragma unroll
        for (int j = 0; j < 2; j++) {
            short8 bf = *(const short8*)&smB[(ch * 2 + j) * 512 + lane * 8];
            acc[j] = __builtin_amdgcn_mfma_f32_16x16x32_bf16(af, bf, acc[j], 0, 0, 0);
        }
    }
#pragma unroll
    for (int j = 0; j < 2; j++) {
        int col = ch * 32 + j * 16 + lr;
        float bv = b2f(bact[col]);
#pragma unroll
        for (int rr = 0; rr < 4; rr++) {
            int r = row0 + g * 16 + lq * 4 + rr;
            float val = acc[j][rr] + bv;
            if (bf16out) ((unsigned short*)out)[(size_t)r * 64 + col] = f2b(val);
            else         ((float*)out)[(size_t)r * 64 + col] = val;
        }
    }
}

extern "C" void kernel_launch(void* const* d_in, const int* in_sizes, int n_in,
                              void* d_out, int out_size, void* d_ws, size_t ws_size,
                              hipStream_t stream) {
    const void* x    = d_in[0];
    const int*  adj  = (const int*)d_in[1];
    const void* W    = d_in[2];
    const void* a1   = d_in[3];
    const void* a2   = d_in[4];
    const void* Wact = d_in[5];
    const void* bact = d_in[6];

    char* ws = (char*)d_ws;
    unsigned short* WhT   = (unsigned short*)(ws);               // 16 MB  [32][256][1024]
    unsigned short* xb    = (unsigned short*)(ws + 16777216);    // 16 MB  (== feat)
    unsigned short* feat  = (unsigned short*)(ws + 16777216);    // 16 MB  [8192][1024]
    unsigned short* WT    = (unsigned short*)(ws + 33554432);    //  2 MB  [4][256][1024]
    unsigned int*   amask = (unsigned int*)(ws + 33554432);      //  1 MB  (== WT, after k1)
    unsigned short* WactT = (unsigned short*)(ws + 35651584);    // 128 KB [64][1024]
    float*          f1    = (float*)(ws + 35782656);             // 128 KB [32][1024]
    float*          f2    = (float*)(ws + 35913728);             // 128 KB [32][1024]
    unsigned short* a1b   = (unsigned short*)(ws + 36044800);    // 2 KB
    unsigned short* a2b   = (unsigned short*)(ws + 36046848);    // 2 KB
    unsigned short* bactb = (unsigned short*)(ws + 36048896);    // 128 B
    int*            flag  = (int*)(ws + 36049024);               // 16 B
    if (ws_size < (size_t)36049040) return;

    detect_kern<<<1, 64, 0, stream>>>((const unsigned int*)x, flag);
    conv8<<<4096, 256, 0, stream>>>(x, xb, flag, 1048576);
    conv8<<<1, 256, 0, stream>>>(a1, a1b, flag, 128);
    conv8<<<1, 256, 0, stream>>>(a2, a2b, flag, 128);
    conv8<<<1, 256, 0, stream>>>(bact, bactb, flag, 8);
    t2_kern<<<dim3(4, 16, 4), 256, 0, stream>>>(W, WT, flag, 256);
    t2_kern<<<dim3(1, 16, 1), 256, 0, stream>>>(Wact, WactT, flag, 64);
    k1_gemm<<<dim3(8, 64), 256, 0, stream>>>(xb, WT, WhT);
    pack_adj<<<32768, 256, 0, stream>>>(adj, (unsigned long long*)amask);
    k1b_f12<<<dim3(4, 32), 256, 0, stream>>>(WhT, a1b, a2b, f1, f2);
    k2_attn<<<512, 256, 0, stream>>>(WhT, amask, f1, f2, feat);
    k3_out<<<256, 256, 0, stream>>>(feat, WactT, bactb, d_out, flag);
}

// Round 6
// 239.801 us; speedup vs baseline: 1.1952x; 1.1952x over previous
//
#include <hip/hip_runtime.h>
#include <stdint.h>

// Problem constants: B=8, N=1024, IN_F=1024, E=256, H=4, A=64
typedef __attribute__((ext_vector_type(8))) short short8;
typedef __attribute__((ext_vector_type(4))) float f32x4;
typedef __attribute__((ext_vector_type(16))) float f32x16;

// WhF frag-tile layout (canonical, used by k1 epilogue, k1b, k2):
//   element (hb, e, m), e in [0,256), m in [0,1024):
//   et=e>>5, e31=e&31, m16=m>>4, l5=(m>>3)&1, m7=m&7
//   u16 idx = ((hb*8+et)*64 + m16)*512 + (l5*32+e31)*8 + m7
// => one (et,m16) tile is 1KB contiguous in MFMA-B lane order (lane=l5*32+e31).

__device__ __forceinline__ float b2f(unsigned short u) {
    union { unsigned int i; float f; } v; v.i = ((unsigned int)u) << 16; return v.f;
}
__device__ __forceinline__ unsigned short f2b(float f) {
    union { float f; unsigned int i; } v; v.f = f;
    unsigned int u = v.i;
    u = (u + 0x7FFFu + ((u >> 16) & 1u)) >> 16;
    return (unsigned short)u;
}
__device__ __forceinline__ void glds16(const void* g, const void* l) {
    __builtin_amdgcn_global_load_lds(
        (const __attribute__((address_space(1))) unsigned int*)g,
        (__attribute__((address_space(3))) unsigned int*)l, 16, 0, 0);
}

__device__ __forceinline__ void cvt8(const void* in, unsigned short* out,
                                     int f, int grp) {
    if (f) {
        ((ushort4*)out)[grp * 2]     = ((const ushort4*)in)[grp * 2];
        ((ushort4*)out)[grp * 2 + 1] = ((const ushort4*)in)[grp * 2 + 1];
    } else {
        const float4* p = (const float4*)in + (size_t)grp * 2;
        float4 a = p[0], b = p[1];
        ushort4 o0, o1;
        o0.x = f2b(a.x); o0.y = f2b(a.y); o0.z = f2b(a.z); o0.w = f2b(a.w);
        o1.x = f2b(b.x); o1.y = f2b(b.y); o1.z = f2b(b.z); o1.w = f2b(b.w);
        ((ushort4*)out)[grp * 2]     = o0;
        ((ushort4*)out)[grp * 2 + 1] = o1;
    }
}

// prep_small: dtype detect (wave 0) + convert a1/a2/b_act. One block.
__global__ void prep_small(const unsigned int* __restrict__ x,
                           const void* __restrict__ a1, const void* __restrict__ a2,
                           const void* __restrict__ bact,
                           unsigned short* __restrict__ a1b,
                           unsigned short* __restrict__ a2b,
                           unsigned short* __restrict__ bactb,
                           int* __restrict__ flag) {
    __shared__ int sflag;
    int tid = threadIdx.x;
    if (tid < 64) {
        unsigned int wv = x[tid];
        unsigned int e = (wv >> 7) & 0xFF;
        unsigned long long m = __ballot(e >= 100 && e <= 140);
        if (tid == 0) { sflag = (__popcll(m) >= 48) ? 1 : 0; flag[0] = sflag; }
    }
    __syncthreads();
    int f = sflag;
    if (tid < 128) cvt8(a1, a1b, f, tid);
    else           cvt8(a2, a2b, f, tid - 128);
    if (tid < 8)   cvt8(bact, bactb, f, tid);
}

// Convert x (8.4M elems) to bf16, 8 per thread.
__global__ void conv8(const void* __restrict__ in, unsigned short* __restrict__ out,
                      const int* __restrict__ flag, int total8) {
    int i = blockIdx.x * 256 + threadIdx.x;
    if (i >= total8) return;
    cvt8(in, out, *flag, i);
}

// LDS-tiled transpose + convert for W (z<4, C=256) and W_act (z==4, C=64).
__global__ __launch_bounds__(256) void t2_all(
        const void* __restrict__ Win, const void* __restrict__ Wactin,
        unsigned short* __restrict__ WT, unsigned short* __restrict__ WactT,
        const int* __restrict__ flag) {
    __shared__ unsigned int tile[64 * 65];
    int z = blockIdx.z;
    const void* in; unsigned short* out; int C, bt;
    if (z < 4) { in = Win; out = WT; C = 256; bt = z; }
    else { if (blockIdx.x != 0) return; in = Wactin; out = WactT; C = 64; bt = 0; }
    int t = threadIdx.x;
    int c0 = blockIdx.x * 64;
    int r0 = blockIdx.y * 64;
    int rl = t >> 2;
    int cc = (t & 3) * 16;
    size_t ibase = ((size_t)bt * 1024 + (r0 + rl)) * C + c0 + cc;
    unsigned short v[16];
    if (*flag) {
        const unsigned short* p = (const unsigned short*)in + ibase;
        short8 a = *(const short8*)p;
        short8 b = *(const short8*)(p + 8);
#pragma unroll
        for (int j = 0; j < 8; j++) { v[j] = (unsigned short)a[j]; v[8 + j] = (unsigned short)b[j]; }
    } else {
        const float* p = (const float*)in + ibase;
#pragma unroll
        for (int j = 0; j < 16; j++) v[j] = f2b(p[j]);
    }
#pragma unroll
    for (int j = 0; j < 16; j++)
        tile[(cc + j) * 65 + rl] = v[j];
    __syncthreads();
    int cl = t >> 2;
    int rch = (t & 3) * 16;
    unsigned short o[16];
#pragma unroll
    for (int j = 0; j < 16; j++)
        o[j] = (unsigned short)tile[cl * 65 + rch + j];
    unsigned short* op = out + ((size_t)bt * C + (c0 + cl)) * 1024 + r0 + rch;
#pragma unroll
    for (int q = 0; q < 4; q++) {
        ushort4 s; s.x = o[q*4]; s.y = o[q*4+1]; s.z = o[q*4+2]; s.w = o[q*4+3];
        ((ushort4*)op)[q] = s;
    }
}

// Pack adj into TRANSPOSED bitmask maskT[b][mword=m>>5][n] (u32), via ballot.
// Wave covers 64 consecutive m for fixed (b,n).
__global__ void pack_adj(const int* __restrict__ adj,
                         unsigned int* __restrict__ maskT) {
    int gid = blockIdx.x * 256 + threadIdx.x;
    int lane = threadIdx.x & 63;
    unsigned long long m = __ballot(adj[gid] > 0);
    if (lane == 0) {
        int lin = gid >> 6;           // (b*1024+n)*16 + m0/64
        int mw = (lin & 15) * 2;
        int bn = lin >> 4;
        int b = bn >> 10, n = bn & 1023;
        maskT[(size_t)(b * 32 + mw) * 1024 + n]     = (unsigned int)m;
        maskT[(size_t)(b * 32 + mw + 1) * 1024 + n] = (unsigned int)(m >> 32);
    }
}

// K1: Wh = x @ W[h]  (M=8192, N=1024=H*E, K=1024), writes WhF frag-tile bf16.
__global__ __launch_bounds__(256) void k1_gemm(
        const unsigned short* __restrict__ x,
        const unsigned short* __restrict__ WT,      // [H][E=256][K=1024]
        unsigned short* __restrict__ WhF) {
    __shared__ unsigned short smA[8 * 512];
    __shared__ unsigned short smB[8 * 512];
    int tid = threadIdx.x;
    int w = tid >> 6, lane = tid & 63;
    int lr = lane & 15, lq = lane >> 4;
    int col0 = blockIdx.x * 128;
    int row0 = blockIdx.y * 128;
    int h = col0 >> 8;
    int e_base = col0 & 255;
    int b = row0 >> 10;
    int m_base = row0 & 1023;
    int wr = w >> 1, wc = w & 1;

    f32x4 acc[4][4] = {};

    for (int k0 = 0; k0 < 1024; k0 += 32) {
        __syncthreads();
#pragma unroll
        for (int s = 0; s < 2; s++) {
            int g = 2 * w + s;
            const unsigned short* srcA =
                x + (size_t)(row0 + g * 16 + lr) * 1024 + k0 + lq * 8;
            glds16(srcA, &smA[g * 512]);
            const unsigned short* srcB =
                WT + (size_t)(h * 256 + e_base + g * 16 + lr) * 1024 + k0 + lq * 8;
            glds16(srcB, &smB[g * 512]);
        }
        __syncthreads();
        short8 af[4], bf[4];
#pragma unroll
        for (int i = 0; i < 4; i++)
            af[i] = *(const short8*)&smA[(wr * 4 + i) * 512 + lane * 8];
#pragma unroll
        for (int j = 0; j < 4; j++)
            bf[j] = *(const short8*)&smB[(wc * 4 + j) * 512 + lane * 8];
#pragma unroll
        for (int i = 0; i < 4; i++)
#pragma unroll
            for (int j = 0; j < 4; j++)
                acc[i][j] = __builtin_amdgcn_mfma_f32_16x16x32_bf16(
                    af[i], bf[j], acc[i][j], 0, 0, 0);
    }

    // Epilogue into frag-tile layout. Lane holds e fixed, m = tile + lq*4 + reg.
    int hb = h * 8 + b;
#pragma unroll
    for (int i = 0; i < 4; i++) {
#pragma unroll
        for (int j = 0; j < 4; j++) {
            int e = e_base + (wc * 4 + j) * 16 + lr;
            int et = e >> 5, e31 = e & 31;
            int m16 = (m_base >> 4) + wr * 4 + i;
            ushort4 vs;
            vs.x = f2b(acc[i][j][0]);
            vs.y = f2b(acc[i][j][1]);
            vs.z = f2b(acc[i][j][2]);
            vs.w = f2b(acc[i][j][3]);
            size_t idx = ((size_t)((hb * 8 + et) * 64 + m16) * 512)
                         + ((lq >> 1) * 32 + e31) * 8 + (lq & 1) * 4;
            *(ushort4*)&WhF[idx] = vs;
        }
    }
}

// K1b: f1[hb][n] = sum_e Wh[e][n]*a1[h][e]; f2 likewise. Frag-tile indexing.
__global__ void k1b_f12(const unsigned short* __restrict__ WhF,
                        const unsigned short* __restrict__ a1,
                        const unsigned short* __restrict__ a2,
                        float* __restrict__ f1, float* __restrict__ f2) {
    int hb = blockIdx.y;
    int n = blockIdx.x * 256 + threadIdx.x;     // n == m
    int h = hb >> 3;
    int m16 = n >> 4, l5m = (n >> 3) & 1, m7 = n & 7;
    const unsigned short* base = WhF + (size_t)hb * 8 * 64 * 512
                                 + (size_t)(l5m * 32) * 8 + m7;
    float s1 = 0.f, s2 = 0.f;
    for (int e = 0; e < 256; e++) {
        int et = e >> 5, e31 = e & 31;
        float wv = b2f(base[(size_t)(et * 64 + m16) * 512 + e31 * 8]);
        s1 += wv * b2f(a1[h * 256 + e]);
        s2 += wv * b2f(a2[h * 256 + e]);
    }
    f1[hb * 1024 + n] = s1;
    f2[hb * 1024 + n] = s2;
}

// K2: masked-softmax attention + P@Wh + ELU -> feat[bn][h*256+e] bf16.
// Barrier-free, no LDS. Wave = 32 rows x 128 e, 32x32x16 MFMA. B-frags are
// contiguous 1KB tiles in WhF (lane*16B) -> fully coalesced L2-hit loads
// (XCD swizzle keeps per-XCD working set 4x512KB = 2MB < 4MB L2).
// Register double-buffer prefetches iter+1's frags a full iteration ahead.
__global__ __launch_bounds__(256, 2) void k2_attn(
        const unsigned short* __restrict__ WhF,
        const unsigned int* __restrict__ maskT,     // [8][32][1024]
        const float* __restrict__ f1, const float* __restrict__ f2,
        unsigned short* __restrict__ feat) {
    int tid = threadIdx.x;
    int w = tid >> 6, lane = tid & 63;
    int l5 = lane >> 5, l31 = lane & 31;
    int bid = blockIdx.x;
    int xcd = bid & 7, idx = bid >> 3;          // idx 0..63
    int hb = xcd + 8 * (idx >> 4);
    int sub = idx & 15;
    int wid = sub * 4 + w;                      // 0..63 within hb
    int rg = wid >> 1;                          // row-group 0..31
    int ehalf = wid & 1;
    int n0 = rg * 32;
    int h = hb >> 3, b = hb & 7;
    int row = n0 + l31;
    float f1n = f1[hb * 1024 + row];
    // frag base for (et_local, m16): whb + (et_local*64 + m16)*512   (u16)
    const unsigned short* whb = WhF + (size_t)(hb * 8 + ehalf * 4) * 64 * 512
                                + lane * 8;
    const unsigned int* mrow = maskT + (size_t)b * 32 * 1024 + row;
    const float* f2row = f2 + hb * 1024;

    f32x16 acc[4] = {};                         // e = ehalf*128 + et*32 + l31
    float den = 0.f;

    short8 buf[2][4][2];
#pragma unroll
    for (int et = 0; et < 4; et++)
#pragma unroll
        for (int ks = 0; ks < 2; ks++)
            buf[0][et][ks] = *(const short8*)(whb + (size_t)(et * 64 + ks) * 512);

#pragma unroll 2
    for (int m0 = 0; m0 < 1024; m0 += 32) {
        int p = (m0 >> 5) & 1;
        // prefetch next iteration's B-frags (coalesced 1KB per instr)
        if (m0 + 32 < 1024) {
            int m16n = (m0 >> 4) + 2;
#pragma unroll
            for (int et = 0; et < 4; et++)
#pragma unroll
                for (int ks = 0; ks < 2; ks++)
                    buf[p ^ 1][et][ks] =
                        *(const short8*)(whb + (size_t)(et * 64 + m16n + ks) * 512);
        }
        unsigned int mw = mrow[(size_t)(m0 >> 5) * 1024];
        float4 fA0 = *(const float4*)(f2row + m0 + l5 * 8);
        float4 fA1 = *(const float4*)(f2row + m0 + l5 * 8 + 4);
        float4 fB0 = *(const float4*)(f2row + m0 + 16 + l5 * 8);
        float4 fB1 = *(const float4*)(f2row + m0 + 16 + l5 * 8 + 4);
        float fm[16] = {fA0.x,fA0.y,fA0.z,fA0.w, fA1.x,fA1.y,fA1.z,fA1.w,
                        fB0.x,fB0.y,fB0.z,fB0.w, fB1.x,fB1.y,fB1.z,fB1.w};
        short8 af[2];
#pragma unroll
        for (int ks = 0; ks < 2; ks++) {
#pragma unroll
            for (int j = 0; j < 8; j++) {
                float t_ = f1n + fm[ks * 8 + j];
                float e_ = fmaxf(t_, 0.2f * t_);                   // leaky relu
                float pv = ((mw >> (ks * 16 + l5 * 8 + j)) & 1u) ? __expf(e_) : 0.f;
                unsigned short pb = f2b(pv);
                af[ks][j] = (short)pb;
                den += b2f(pb);      // bf16-rounded p: consistent num/denom
            }
        }
#pragma unroll
        for (int et = 0; et < 4; et++)
#pragma unroll
            for (int ks = 0; ks < 2; ks++)
                acc[et] = __builtin_amdgcn_mfma_f32_32x32x16_bf16(
                    af[ks], buf[p][et][ks], acc[et], 0, 0, 0);
    }

    // den: lane holds partial for row l31 over its k-half; combine halves
    den += __shfl_xor(den, 32, 64);

#pragma unroll
    for (int reg = 0; reg < 16; reg++) {
        int r = (reg & 3) + 8 * (reg >> 2) + 4 * l5;   // C-layout row (0..31)
        float dr = __shfl(den, r, 64);
        float rdr = 1.0f / dr;
        int nn = n0 + r;
#pragma unroll
        for (int et = 0; et < 4; et++) {
            int e = ehalf * 128 + et * 32 + l31;
            float v = acc[et][reg] * rdr;
            float o = v > 0.f ? v : __expf(v) - 1.f;   // elu
            feat[(size_t)(b * 1024 + nn) * 1024 + h * 256 + e] = f2b(o);
        }
    }
}

// K3: out = feat @ W_act + b_act  (M=8192, K=1024, N=64), out dtype per flag.
__global__ __launch_bounds__(256) void k3_out(
        const unsigned short* __restrict__ feat,
        const unsigned short* __restrict__ WactT,   // [64][1024]
        const unsigned short* __restrict__ bact,
        void* __restrict__ out, const int* __restrict__ flag) {
    __shared__ unsigned short smA[2 * 512];
    __shared__ unsigned short smB[4 * 512];
    int tid = threadIdx.x;
    int w = tid >> 6, lane = tid & 63;
    int lr = lane & 15, lq = lane >> 4;
    int row0 = blockIdx.x * 32;
    int g = w & 1, ch = w >> 1;
    int bf16out = *flag;
    f32x4 acc[2] = {};

    for (int k0 = 0; k0 < 1024; k0 += 32) {
        __syncthreads();
        if (w < 2) {
            const unsigned short* src =
                feat + (size_t)(row0 + w * 16 + lr) * 1024 + k0 + lq * 8;
            glds16(src, &smA[w * 512]);
        } else {
#pragma unroll
            for (int s = 0; s < 2; s++) {
                int t = (w - 2) * 2 + s;
                const unsigned short* src =
                    WactT + (size_t)(t * 16 + lr) * 1024 + k0 + lq * 8;
                glds16(src, &smB[t * 512]);
            }
        }
        __syncthreads();
        short8 af = *(const short8*)&smA[g * 512 + lane * 8];
#pragma unroll
        for (int j = 0; j < 2; j++) {
            short8 bf = *(const short8*)&smB[(ch * 2 + j) * 512 + lane * 8];
            acc[j] = __builtin_amdgcn_mfma_f32_16x16x32_bf16(af, bf, acc[j], 0, 0, 0);
        }
    }
#pragma unroll
    for (int j = 0; j < 2; j++) {
        int col = ch * 32 + j * 16 + lr;
        float bv = b2f(bact[col]);
#pragma unroll
        for (int rr = 0; rr < 4; rr++) {
            int r = row0 + g * 16 + lq * 4 + rr;
            float val = acc[j][rr] + bv;
            if (bf16out) ((unsigned short*)out)[(size_t)r * 64 + col] = f2b(val);
            else         ((float*)out)[(size_t)r * 64 + col] = val;
        }
    }
}

extern "C" void kernel_launch(void* const* d_in, const int* in_sizes, int n_in,
                              void* d_out, int out_size, void* d_ws, size_t ws_size,
                              hipStream_t stream) {
    const void* x    = d_in[0];
    const int*  adj  = (const int*)d_in[1];
    const void* W    = d_in[2];
    const void* a1   = d_in[3];
    const void* a2   = d_in[4];
    const void* Wact = d_in[5];
    const void* bact = d_in[6];

    char* ws = (char*)d_ws;
    unsigned short* WhF   = (unsigned short*)(ws);               // 16 MB  frag-tile
    unsigned short* xb    = (unsigned short*)(ws + 16777216);    // 16 MB  (== feat)
    unsigned short* feat  = (unsigned short*)(ws + 16777216);    // 16 MB  [8192][1024]
    unsigned short* WT    = (unsigned short*)(ws + 33554432);    //  2 MB  [4][256][1024]
    unsigned int*   maskT = (unsigned int*)(ws + 33554432);      //  1 MB  (== WT, after k1)
    unsigned short* WactT = (unsigned short*)(ws + 35651584);    // 128 KB [64][1024]
    float*          f1    = (float*)(ws + 35782656);             // 128 KB [32][1024]
    float*          f2    = (float*)(ws + 35913728);             // 128 KB [32][1024]
    unsigned short* a1b   = (unsigned short*)(ws + 36044800);    // 2 KB
    unsigned short* a2b   = (unsigned short*)(ws + 36046848);    // 2 KB
    unsigned short* bactb = (unsigned short*)(ws + 36048896);    // 128 B
    int*            flag  = (int*)(ws + 36049024);               // 16 B
    if (ws_size < (size_t)36049040) return;

    prep_small<<<1, 256, 0, stream>>>((const unsigned int*)x, a1, a2, bact,
                                      a1b, a2b, bactb, flag);
    conv8<<<4096, 256, 0, stream>>>(x, xb, flag, 1048576);
    t2_all<<<dim3(4, 16, 5), 256, 0, stream>>>(W, Wact, WT, WactT, flag);
    k1_gemm<<<dim3(8, 64), 256, 0, stream>>>(xb, WT, WhF);
    pack_adj<<<32768, 256, 0, stream>>>(adj, maskT);   // overwrites WT (dead)
    k1b_f12<<<dim3(4, 32), 256, 0, stream>>>(WhF, a1b, a2b, f1, f2);
    k2_attn<<<512, 256, 0, stream>>>(WhF, maskT, f1, f2, feat);
    k3_out<<<256, 256, 0, stream>>>(feat, WactT, bactb, d_out, flag);
}